// Round 2
// baseline (166.755 us; speedup 1.0000x reference)
//
#include <hip/hip_runtime.h>

// PyramidToDepth: x (8,512,512,2) fp32 -> out (8,18,512,512,1) fp32
// levels lv=0..8, S=512>>lv; out[b, 2*lv+c, h, w] = bilinear_up(level_lv)[b,h,w,c]
//
// d_ws holds levels 1..6, channel-interleaved (B,S,S,2), float2-unit offsets:
//   lv:    1       2       3       4       5       6
//   off2:  0  524288  655360  688128  696320  698368
//
// Round theory: (1) old build kernel was 512 blocks = 2/CU -> latency-bound
// x read + 5-barrier serial tail; split into A1 (lv0+lv1, 1024 blocks, no
// barriers, pure streaming) + A2 (lv2..6 chain from global lv1, tiny traffic).
// (2) upsample now does 4 output rows/block with a shift-by-1 clamp-baked LDS
// window (no clamps in the gather) and a constant-weight lv1 fast path.

#define HWTOT (512 * 512)
#define RW 260  // LDS row stride (float2) for the 4-row staging window

typedef float vfloat4 __attribute__((ext_vector_type(4)));

__constant__ int c_off2[7] = {0, 0, 524288, 655360, 688128, 696320, 698368};

// --- Kernel A1: lv0 identity planes + lv1. grid (128,8); tile 64w x 32h. ----
__global__ __launch_bounds__(256) void build_lv01(const float* __restrict__ x,
                                                  float2* __restrict__ pyr,
                                                  float* __restrict__ out) {
  const int b = blockIdx.y;
  const int tx = blockIdx.x & 7;   // 64-px col tile
  const int ty = blockIdx.x >> 3;  // 32-px row tile (0..15)
  const int t = threadIdx.x;
  const int i = t >> 4;  // lv1 row in tile (0..15)
  const int j = t & 15;  // lv1 col-pair (0..15)
  const int xr = ty * 32 + 2 * i;
  const int xc = tx * 64 + 4 * j;
  const float* r0 = x + ((size_t)(b * 512 + xr) * 512 + xc) * 2;
  const float* r1 = r0 + 1024;
  float4 a0 = *(const float4*)r0;
  float4 a1 = *(const float4*)(r0 + 4);
  float4 c0 = *(const float4*)r1;
  float4 c1 = *(const float4*)(r1 + 4);
  float2 o0 = {(a0.x + a0.z + c0.x + c0.z) * 0.25f, (a0.y + a0.w + c0.y + c0.w) * 0.25f};
  float2 o1 = {(a1.x + a1.z + c1.x + c1.z) * 0.25f, (a1.y + a1.w + c1.y + c1.w) * 0.25f};
  float2* g = pyr + ((size_t)(b * 256 + ty * 16 + i) * 256 + tx * 32 + 2 * j);
  *(vfloat4*)g = (vfloat4){o0.x, o0.y, o1.x, o1.y};
  const size_t ob = (size_t)(b * 18) * HWTOT + (size_t)xr * 512 + xc;
  *(vfloat4*)(out + ob) = (vfloat4){a0.x, a0.z, a1.x, a1.z};
  *(vfloat4*)(out + ob + 512) = (vfloat4){c0.x, c0.z, c1.x, c1.z};
  *(vfloat4*)(out + ob + HWTOT) = (vfloat4){a0.y, a0.w, a1.y, a1.w};
  *(vfloat4*)(out + ob + HWTOT + 512) = (vfloat4){c0.y, c0.w, c1.y, c1.w};
}

// --- Kernel A2: lv2..lv6 from global lv1. grid (64,8); 32x32 lv1 tile. ------
__global__ __launch_bounds__(256) void build_lv2_6(float2* pyr) {
  const int b = blockIdx.y;
  const int tx = blockIdx.x & 7, ty = blockIdx.x >> 3;
  const int t = threadIdx.x;

  __shared__ float2 sh1[32 * 32];
  __shared__ float2 sh2[16 * 16];
  __shared__ float2 sh3[8 * 8];
  __shared__ float2 sh4[4 * 4];
  __shared__ float2 sh5[2 * 2];

  {  // stage 32x32 lv1 tile (4 float2 / thread, coalesced)
    const int row = t >> 3, c4 = (t & 7) << 2;
    const float2* src = pyr + (size_t)(b * 256 + ty * 32 + row) * 256 + tx * 32 + c4;
    float4 v0 = *(const float4*)src;
    float4 v1 = *(const float4*)(src + 2);
    *(float4*)&sh1[t * 4] = v0;
    *(float4*)&sh1[t * 4 + 2] = v1;
  }
  __syncthreads();
  // level 2: 16x16
  {
    const int i = t >> 4, j = t & 15;
    float2 a = sh1[(2 * i) * 32 + 2 * j], c = sh1[(2 * i) * 32 + 2 * j + 1];
    float2 d = sh1[(2 * i + 1) * 32 + 2 * j], e = sh1[(2 * i + 1) * 32 + 2 * j + 1];
    float2 o = {(a.x + c.x + d.x + e.x) * 0.25f, (a.y + c.y + d.y + e.y) * 0.25f};
    sh2[i * 16 + j] = o;
    pyr[524288 + (size_t)(b * 128 + ty * 16 + i) * 128 + tx * 16 + j] = o;
  }
  __syncthreads();
  // level 3: 8x8
  if (t < 64) {
    const int i = t >> 3, j = t & 7;
    float2 a = sh2[(2 * i) * 16 + 2 * j], c = sh2[(2 * i) * 16 + 2 * j + 1];
    float2 d = sh2[(2 * i + 1) * 16 + 2 * j], e = sh2[(2 * i + 1) * 16 + 2 * j + 1];
    float2 o = {(a.x + c.x + d.x + e.x) * 0.25f, (a.y + c.y + d.y + e.y) * 0.25f};
    sh3[i * 8 + j] = o;
    pyr[655360 + (size_t)(b * 64 + ty * 8 + i) * 64 + tx * 8 + j] = o;
  }
  __syncthreads();
  // level 4: 4x4
  if (t < 16) {
    const int i = t >> 2, j = t & 3;
    float2 a = sh3[(2 * i) * 8 + 2 * j], c = sh3[(2 * i) * 8 + 2 * j + 1];
    float2 d = sh3[(2 * i + 1) * 8 + 2 * j], e = sh3[(2 * i + 1) * 8 + 2 * j + 1];
    float2 o = {(a.x + c.x + d.x + e.x) * 0.25f, (a.y + c.y + d.y + e.y) * 0.25f};
    sh4[i * 4 + j] = o;
    pyr[688128 + (size_t)(b * 32 + ty * 4 + i) * 32 + tx * 4 + j] = o;
  }
  __syncthreads();
  // level 5: 2x2
  if (t < 4) {
    const int i = t >> 1, j = t & 1;
    float2 a = sh4[(2 * i) * 4 + 2 * j], c = sh4[(2 * i) * 4 + 2 * j + 1];
    float2 d = sh4[(2 * i + 1) * 4 + 2 * j], e = sh4[(2 * i + 1) * 4 + 2 * j + 1];
    float2 o = {(a.x + c.x + d.x + e.x) * 0.25f, (a.y + c.y + d.y + e.y) * 0.25f};
    sh5[i * 2 + j] = o;
    pyr[696320 + (size_t)(b * 16 + ty * 2 + i) * 16 + tx * 2 + j] = o;
  }
  __syncthreads();
  // level 6: 1x1
  if (t == 0) {
    float2 a = sh5[0], c = sh5[1], d = sh5[2], e = sh5[3];
    float2 o = {(a.x + c.x + d.x + e.x) * 0.25f, (a.y + c.y + d.y + e.y) * 0.25f};
    pyr[698368 + (size_t)(b * 8 + ty) * 8 + tx] = o;
  }
}

// --- Kernel B: levels 1..8, blockIdx.z = lv-1; 4 output rows per block. -----
// LDS holds a 4-row x (S+2)-col window, column-SHIFTED by +1 with edge clamps
// baked in: rows[r][c] = src[clamp(hbase+r,0,S-1)][clamp(c-1,0,S-1)].
// The gather then needs NO clamps: v00 = rows[R0 + floor(sw)+1], v01 at +1.
__global__ __launch_bounds__(256) void upsample_lv(const float2* __restrict__ pyr,
                                                   float* __restrict__ out) {
  const int t = threadIdx.x;
  const int tp = t & 127;  // col group: pixels 4*tp..4*tp+3
  const int rr0 = t >> 7;  // 0/1
  const int w0pix = tp << 2;
  const int bx = blockIdx.x;  // rows 4*bx..4*bx+3
  const int b = blockIdx.y;
  const int lv = blockIdx.z + 1;  // 1..8, block-uniform
  const int S = 512 >> lv;
  const float scale = 1.0f / (float)(1 << lv);

  __shared__ float2 rows[4 * RW + 20];  // window + img7(16) + img8(4)

  const int W = S + 2;
  const int hbase = (int)floorf(((float)(bx << 2) + 0.5f) * scale - 0.5f);

  if (lv <= 6) {
#pragma unroll
    for (int r = 0; r < 4; ++r) {
      int sr = hbase + r;
      sr = sr < 0 ? 0 : (sr > S - 1 ? S - 1 : sr);
      const float2* src = pyr + c_off2[lv] + (size_t)b * S * S + (size_t)sr * S;
      for (int c = t; c < W; c += 256) {
        int sc = c - 1;
        sc = sc < 0 ? 0 : (sc > S - 1 ? S - 1 : sc);
        rows[r * RW + c] = src[sc];
      }
    }
  } else {
    // rebuild lv7 (and lv8) from lv6; block-uniform branches -> sync safe
    float2* img7 = rows + 4 * RW;
    float2* img8 = img7 + 16;
    const float2* l6 = pyr + 698368 + (size_t)b * 64;
    if (t < 16) {
      const int i = t >> 2, j = t & 3;
      float2 a = l6[(2 * i) * 8 + 2 * j], c = l6[(2 * i) * 8 + 2 * j + 1];
      float2 d = l6[(2 * i + 1) * 8 + 2 * j], e = l6[(2 * i + 1) * 8 + 2 * j + 1];
      img7[t] = {(a.x + c.x + d.x + e.x) * 0.25f, (a.y + c.y + d.y + e.y) * 0.25f};
    }
    __syncthreads();
    if (lv == 8 && t < 4) {
      const int i = t >> 1, j = t & 1;
      float2 a = img7[(2 * i) * 4 + 2 * j], c = img7[(2 * i) * 4 + 2 * j + 1];
      float2 d = img7[(2 * i + 1) * 4 + 2 * j], e = img7[(2 * i + 1) * 4 + 2 * j + 1];
      img8[t] = {(a.x + c.x + d.x + e.x) * 0.25f, (a.y + c.y + d.y + e.y) * 0.25f};
    }
    __syncthreads();
    const float2* img = (lv == 7) ? img7 : img8;
    if (t < 4 * W) {
      int r, c;
      if (lv == 7) {
        r = t / 6;
        c = t - r * 6;
      } else {
        r = t >> 2;
        c = t & 3;
      }
      int sr = hbase + r;
      sr = sr < 0 ? 0 : (sr > S - 1 ? S - 1 : sr);
      int sc = c - 1;
      sc = sc < 0 ? 0 : (sc > S - 1 ? S - 1 : sc);
      rows[r * RW + c] = img[sr * S + sc];
    }
  }
  __syncthreads();

  const size_t obase0 =
      (size_t)(b * 18 + 2 * lv) * HWTOT + (size_t)((bx << 2) + rr0) * 512 + w0pix;

  if (lv == 1) {
    // fast path: per-lane window is exactly cols 2tp-1..2tp+2 (LDS 2tp..2tp+3),
    // horizontal weights are the constants {0.25,0.75}; vertical d0/fh are
    // compile-time per rr. 8 ds_read_b64 + constant FMAs per thread.
    const int e0 = tp << 1;
#pragma unroll
    for (int dr2 = 0; dr2 < 2; ++dr2) {
      const int rr = rr0 + 2 * dr2;
      const int d0 = (rr + 1) >> 1;            // {0,1,1,2}
      const float fh = (rr & 1) ? 0.25f : 0.75f;
      const float wy0 = 1.0f - fh;
      const float2* R0 = rows + d0 * RW + e0;
      const float2* R1 = R0 + RW;
      float2 p0 = R0[0], p1 = R0[1], p2 = R0[2], p3 = R0[3];
      float2 q0 = R1[0], q1 = R1[1], q2 = R1[2], q3 = R1[3];
      // horizontal lerps (v00*wx0 + v01*fw), weights constant per k
      float hx0 = p0.x * 0.25f + p1.x * 0.75f, hy0 = p0.y * 0.25f + p1.y * 0.75f;
      float hx1 = p1.x * 0.75f + p2.x * 0.25f, hy1 = p1.y * 0.75f + p2.y * 0.25f;
      float hx2 = p1.x * 0.25f + p2.x * 0.75f, hy2 = p1.y * 0.25f + p2.y * 0.75f;
      float hx3 = p2.x * 0.75f + p3.x * 0.25f, hy3 = p2.y * 0.75f + p3.y * 0.25f;
      float gx0 = q0.x * 0.25f + q1.x * 0.75f, gy0 = q0.y * 0.25f + q1.y * 0.75f;
      float gx1 = q1.x * 0.75f + q2.x * 0.25f, gy1 = q1.y * 0.75f + q2.y * 0.25f;
      float gx2 = q1.x * 0.25f + q2.x * 0.75f, gy2 = q1.y * 0.25f + q2.y * 0.75f;
      float gx3 = q2.x * 0.75f + q3.x * 0.25f, gy3 = q2.y * 0.75f + q3.y * 0.25f;
      const size_t ob = obase0 + (size_t)dr2 * 1024;
      *(vfloat4*)(out + ob) = (vfloat4){hx0 * wy0 + gx0 * fh, hx1 * wy0 + gx1 * fh,
                                        hx2 * wy0 + gx2 * fh, hx3 * wy0 + gx3 * fh};
      *(vfloat4*)(out + ob + HWTOT) = (vfloat4){hy0 * wy0 + gy0 * fh, hy1 * wy0 + gy1 * fh,
                                                hy2 * wy0 + gy2 * fh, hy3 * wy0 + gy3 * fh};
    }
    return;
  }

  // generic path (lv >= 2): horizontal indices/weights shared across both rows
  int w0l[4];
  float fw[4];
#pragma unroll
  for (int k = 0; k < 4; ++k) {
    float sw = ((float)(w0pix + k) + 0.5f) * scale - 0.5f;
    float f = floorf(sw);
    fw[k] = sw - f;
    w0l[k] = (int)f + 1;  // shifted LDS col; clamps baked into staging
  }
#pragma unroll
  for (int dr2 = 0; dr2 < 2; ++dr2) {
    const int rr = rr0 + 2 * dr2;
    const int h = (bx << 2) + rr;
    float shf = ((float)h + 0.5f) * scale - 0.5f;
    float f0 = floorf(shf);
    float fh = shf - f0;
    int d0 = (int)f0 - hbase;  // 0..2; vertical clamps baked into staging
    const float2* R0 = rows + d0 * RW;
    const float2* R1 = R0 + RW;
    const float wy0 = 1.0f - fh;
    float o0[4], o1[4];
#pragma unroll
    for (int k = 0; k < 4; ++k) {
      float2 v00 = R0[w0l[k]], v01 = R0[w0l[k] + 1];
      float2 v10 = R1[w0l[k]], v11 = R1[w0l[k] + 1];
      float wx0 = 1.0f - fw[k];
      float tx_ = v00.x * wx0 + v01.x * fw[k];
      float bx_ = v10.x * wx0 + v11.x * fw[k];
      float ty_ = v00.y * wx0 + v01.y * fw[k];
      float by_ = v10.y * wx0 + v11.y * fw[k];
      o0[k] = tx_ * wy0 + bx_ * fh;
      o1[k] = ty_ * wy0 + by_ * fh;
    }
    const size_t ob = obase0 + (size_t)dr2 * 1024;
    *(vfloat4*)(out + ob) = (vfloat4){o0[0], o0[1], o0[2], o0[3]};
    *(vfloat4*)(out + ob + HWTOT) = (vfloat4){o1[0], o1[1], o1[2], o1[3]};
  }
}

extern "C" void kernel_launch(void* const* d_in, const int* in_sizes, int n_in,
                              void* d_out, int out_size, void* d_ws, size_t ws_size,
                              hipStream_t stream) {
  const float* x = (const float*)d_in[0];
  float* out = (float*)d_out;
  float2* pyr = (float2*)d_ws;

  build_lv01<<<dim3(128, 8), 256, 0, stream>>>(x, pyr, out);
  build_lv2_6<<<dim3(64, 8), 256, 0, stream>>>(pyr);
  upsample_lv<<<dim3(128, 8, 8), 256, 0, stream>>>(pyr, out);
}

// Round 3
// 164.681 us; speedup vs baseline: 1.0126x; 1.0126x over previous
//
#include <hip/hip_runtime.h>

// PyramidToDepth: x (8,512,512,2) fp32 -> out (8,18,512,512,1) fp32
// levels lv=0..8, S=512>>lv; out[b, 2*lv+c, h, w] = bilinear_up(level_lv)[b,h,w,c]
//
// d_ws holds levels 1..6, channel-interleaved (B,S,S,2), float2-unit offsets:
//   lv:    1       2       3       4       5       6
//   off2:  0  524288  655360  688128  696320  698368
//
// Round theory: R2's 3-launch split cost ~4us of graph-node overhead -> back
// to 2 launches (round-1 fused build, verbatim). Upsample: 8 output rows per
// block (half the blocks, 1.5x instead of 2x lv1 staging redundancy, weights
// amortized over 4 row-pairs) + skewed lv1 LDS window (c + c>>3) to kill the
// 8-way bank conflict on the 16B-stride fast-path reads.

#define HWTOT (512 * 512)
#define RW 292  // LDS row stride (float2); >= 258 + (258>>3) = 291 for skewed lv1

typedef float vfloat4 __attribute__((ext_vector_type(4)));

__constant__ int c_off2[7] = {0, 0, 524288, 655360, 688128, 696320, 698368};

// --- Kernel A: levels 1..6 + lv0 identity planes. One block per 64x64 tile. --
__global__ __launch_bounds__(256) void build_levels_1_6(const float* __restrict__ x,
                                                        float2* __restrict__ pyr,
                                                        float* __restrict__ out) {
  const int b = blockIdx.y;
  const int tx = blockIdx.x & 7, ty = blockIdx.x >> 3;
  const int t = threadIdx.x;

  __shared__ float2 sh1[32 * 32];
  __shared__ float2 sh2[16 * 16];
  __shared__ float2 sh3[8 * 8];
  __shared__ float2 sh4[4 * 4];
  __shared__ float2 sh5[2 * 2];

  // level 1: 32x32 tile-local, 4 consecutive cols per thread. Also emit lv0.
  {
    const int i = t >> 3;
    const int j0 = (t & 7) << 2;
    const int row0 = ty * 64 + 2 * i;      // x row (even)
    const int colx = tx * 64 + 2 * j0;     // x pixel col base (8 pixels)
    const float* r0 = x + (((size_t)(b * 512 + row0)) * 512 + colx) * 2;
    const float* r1 = r0 + 1024;
    float4 a[4], c[4];
    float2 o[4];
#pragma unroll
    for (int k = 0; k < 4; ++k) {
      a[k] = *(const float4*)(r0 + 4 * k);
      c[k] = *(const float4*)(r1 + 4 * k);
      o[k].x = (a[k].x + a[k].z + c[k].x + c[k].z) * 0.25f;
      o[k].y = (a[k].y + a[k].w + c[k].y + c[k].w) * 0.25f;
      sh1[i * 32 + j0 + k] = o[k];
    }
    float2* g = pyr + ((size_t)(b * 256 + ty * 32 + i) * 256 + tx * 32 + j0);
    *(float4*)(g) = make_float4(o[0].x, o[0].y, o[1].x, o[1].y);
    *(float4*)(g + 2) = make_float4(o[2].x, o[2].y, o[3].x, o[3].y);

    // lv0 identity resize: channels 0 (x) and 1 (y), rows row0 and row0+1.
    const size_t ob = (size_t)(b * 18) * HWTOT + (size_t)row0 * 512 + colx;
    *(vfloat4*)(out + ob)                  = (vfloat4){a[0].x, a[0].z, a[1].x, a[1].z};
    *(vfloat4*)(out + ob + 4)              = (vfloat4){a[2].x, a[2].z, a[3].x, a[3].z};
    *(vfloat4*)(out + ob + 512)            = (vfloat4){c[0].x, c[0].z, c[1].x, c[1].z};
    *(vfloat4*)(out + ob + 512 + 4)        = (vfloat4){c[2].x, c[2].z, c[3].x, c[3].z};
    *(vfloat4*)(out + ob + HWTOT)          = (vfloat4){a[0].y, a[0].w, a[1].y, a[1].w};
    *(vfloat4*)(out + ob + HWTOT + 4)      = (vfloat4){a[2].y, a[2].w, a[3].y, a[3].w};
    *(vfloat4*)(out + ob + HWTOT + 512)    = (vfloat4){c[0].y, c[0].w, c[1].y, c[1].w};
    *(vfloat4*)(out + ob + HWTOT + 512 + 4)= (vfloat4){c[2].y, c[2].w, c[3].y, c[3].w};
  }
  __syncthreads();
  // level 2: 16x16
  {
    const int i = t >> 4, j = t & 15;
    float2 a = sh1[(2 * i) * 32 + 2 * j], c = sh1[(2 * i) * 32 + 2 * j + 1];
    float2 d = sh1[(2 * i + 1) * 32 + 2 * j], e = sh1[(2 * i + 1) * 32 + 2 * j + 1];
    float2 o = {(a.x + c.x + d.x + e.x) * 0.25f, (a.y + c.y + d.y + e.y) * 0.25f};
    sh2[i * 16 + j] = o;
    pyr[524288 + (size_t)(b * 128 + ty * 16 + i) * 128 + tx * 16 + j] = o;
  }
  __syncthreads();
  // level 3: 8x8
  if (t < 64) {
    const int i = t >> 3, j = t & 7;
    float2 a = sh2[(2 * i) * 16 + 2 * j], c = sh2[(2 * i) * 16 + 2 * j + 1];
    float2 d = sh2[(2 * i + 1) * 16 + 2 * j], e = sh2[(2 * i + 1) * 16 + 2 * j + 1];
    float2 o = {(a.x + c.x + d.x + e.x) * 0.25f, (a.y + c.y + d.y + e.y) * 0.25f};
    sh3[i * 8 + j] = o;
    pyr[655360 + (size_t)(b * 64 + ty * 8 + i) * 64 + tx * 8 + j] = o;
  }
  __syncthreads();
  // level 4: 4x4
  if (t < 16) {
    const int i = t >> 2, j = t & 3;
    float2 a = sh3[(2 * i) * 8 + 2 * j], c = sh3[(2 * i) * 8 + 2 * j + 1];
    float2 d = sh3[(2 * i + 1) * 8 + 2 * j], e = sh3[(2 * i + 1) * 8 + 2 * j + 1];
    float2 o = {(a.x + c.x + d.x + e.x) * 0.25f, (a.y + c.y + d.y + e.y) * 0.25f};
    sh4[i * 4 + j] = o;
    pyr[688128 + (size_t)(b * 32 + ty * 4 + i) * 32 + tx * 4 + j] = o;
  }
  __syncthreads();
  // level 5: 2x2
  if (t < 4) {
    const int i = t >> 1, j = t & 1;
    float2 a = sh4[(2 * i) * 4 + 2 * j], c = sh4[(2 * i) * 4 + 2 * j + 1];
    float2 d = sh4[(2 * i + 1) * 4 + 2 * j], e = sh4[(2 * i + 1) * 4 + 2 * j + 1];
    float2 o = {(a.x + c.x + d.x + e.x) * 0.25f, (a.y + c.y + d.y + e.y) * 0.25f};
    sh5[i * 2 + j] = o;
    pyr[696320 + (size_t)(b * 16 + ty * 2 + i) * 16 + tx * 2 + j] = o;
  }
  __syncthreads();
  // level 6: 1x1
  if (t == 0) {
    float2 a = sh5[0], c = sh5[1], d = sh5[2], e = sh5[3];
    float2 o = {(a.x + c.x + d.x + e.x) * 0.25f, (a.y + c.y + d.y + e.y) * 0.25f};
    pyr[698368 + (size_t)(b * 8 + ty) * 8 + tx] = o;
  }
}

// --- Kernel B: levels 1..8, blockIdx.z = lv-1; 8 output rows per block. -----
// LDS holds a 6-row x (S+2)-col window, column-SHIFTED by +1 with edge clamps
// baked in: rows[r][c] = src[clamp(hbase+r,0,S-1)][clamp(c-1,0,S-1)].
// lv1 window is additionally SKEWED (idx = c + (c>>3)) so the fast path's
// 16B-stride reads hit distinct banks (was 8-way conflict).
__global__ __launch_bounds__(256) void upsample_lv(const float2* __restrict__ pyr,
                                                   float* __restrict__ out) {
  const int t = threadIdx.x;
  const int tp = t & 127;  // col group: pixels 4*tp..4*tp+3
  const int rr0 = t >> 7;  // 0/1
  const int w0pix = tp << 2;
  const int bx = blockIdx.x;  // rows 8*bx..8*bx+7
  const int b = blockIdx.y;
  const int lv = blockIdx.z + 1;  // 1..8, block-uniform
  const int S = 512 >> lv;
  const float scale = 1.0f / (float)(1 << lv);

  __shared__ float2 rows[6 * RW + 20];  // window + img7(16) + img8(4)

  const int W = S + 2;
  const int hbase = (int)floorf(((float)(bx << 3) + 0.5f) * scale - 0.5f);

  if (lv == 1) {
    // skewed staging (S=256, W=258): rows[r][c + (c>>3)] = src[...]
#pragma unroll
    for (int r = 0; r < 6; ++r) {
      int sr = hbase + r;
      sr = sr < 0 ? 0 : (sr > S - 1 ? S - 1 : sr);
      const float2* src = pyr + (size_t)b * S * S + (size_t)sr * S;
      for (int c = t; c < W; c += 256) {
        int sc = c - 1;
        sc = sc < 0 ? 0 : (sc > S - 1 ? S - 1 : sc);
        rows[r * RW + c + (c >> 3)] = src[sc];
      }
    }
  } else if (lv <= 6) {
#pragma unroll
    for (int r = 0; r < 6; ++r) {
      int sr = hbase + r;
      sr = sr < 0 ? 0 : (sr > S - 1 ? S - 1 : sr);
      const float2* src = pyr + c_off2[lv] + (size_t)b * S * S + (size_t)sr * S;
      if (t < W) {  // W <= 130 here
        int sc = t - 1;
        sc = sc < 0 ? 0 : (sc > S - 1 ? S - 1 : sc);
        rows[r * RW + t] = src[sc];
      }
    }
  } else {
    // rebuild lv7 (and lv8) from lv6; block-uniform branches -> sync safe
    float2* img7 = rows + 6 * RW;
    float2* img8 = img7 + 16;
    const float2* l6 = pyr + 698368 + (size_t)b * 64;
    if (t < 16) {
      const int i = t >> 2, j = t & 3;
      float2 a = l6[(2 * i) * 8 + 2 * j], c = l6[(2 * i) * 8 + 2 * j + 1];
      float2 d = l6[(2 * i + 1) * 8 + 2 * j], e = l6[(2 * i + 1) * 8 + 2 * j + 1];
      img7[t] = {(a.x + c.x + d.x + e.x) * 0.25f, (a.y + c.y + d.y + e.y) * 0.25f};
    }
    __syncthreads();
    if (lv == 8 && t < 4) {
      const int i = t >> 1, j = t & 1;
      float2 a = img7[(2 * i) * 4 + 2 * j], c = img7[(2 * i) * 4 + 2 * j + 1];
      float2 d = img7[(2 * i + 1) * 4 + 2 * j], e = img7[(2 * i + 1) * 4 + 2 * j + 1];
      img8[t] = {(a.x + c.x + d.x + e.x) * 0.25f, (a.y + c.y + d.y + e.y) * 0.25f};
    }
    __syncthreads();
    const float2* img = (lv == 7) ? img7 : img8;
    if (t < 6 * W) {  // 36 or 24 entries
      int r = t / W;
      int c = t - r * W;
      int sr = hbase + r;
      sr = sr < 0 ? 0 : (sr > S - 1 ? S - 1 : sr);
      int sc = c - 1;
      sc = sc < 0 ? 0 : (sc > S - 1 ? S - 1 : sc);
      rows[r * RW + c] = img[sr * S + sc];
    }
  }
  __syncthreads();

  const size_t obase0 =
      (size_t)(b * 18 + 2 * lv) * HWTOT + (size_t)((bx << 3) + rr0) * 512 + w0pix;

  if (lv == 1) {
    // fast path: per-lane source cols 2tp-1..2tp+2 (LDS skewed cols 2tp..2tp+3),
    // horizontal weights constant {0.25,0.75}; vertical d0/fh compile-time per rr.
    const int e0 = tp << 1;
    const int i0 = e0 + (e0 >> 3);
    const int i1 = (e0 + 1) + ((e0 + 1) >> 3);
    const int i2 = (e0 + 2) + ((e0 + 2) >> 3);
    const int i3 = (e0 + 3) + ((e0 + 3) >> 3);
#pragma unroll
    for (int dr2 = 0; dr2 < 4; ++dr2) {
      const int rr = rr0 + 2 * dr2;
      const int d0 = (rr + 1) >> 1;            // 0..4
      const float fh = (rr & 1) ? 0.25f : 0.75f;
      const float wy0 = 1.0f - fh;
      const float2* R0 = rows + d0 * RW;
      const float2* R1 = R0 + RW;
      float2 p0 = R0[i0], p1 = R0[i1], p2 = R0[i2], p3 = R0[i3];
      float2 q0 = R1[i0], q1 = R1[i1], q2 = R1[i2], q3 = R1[i3];
      float hx0 = p0.x * 0.25f + p1.x * 0.75f, hy0 = p0.y * 0.25f + p1.y * 0.75f;
      float hx1 = p1.x * 0.75f + p2.x * 0.25f, hy1 = p1.y * 0.75f + p2.y * 0.25f;
      float hx2 = p1.x * 0.25f + p2.x * 0.75f, hy2 = p1.y * 0.25f + p2.y * 0.75f;
      float hx3 = p2.x * 0.75f + p3.x * 0.25f, hy3 = p2.y * 0.75f + p3.y * 0.25f;
      float gx0 = q0.x * 0.25f + q1.x * 0.75f, gy0 = q0.y * 0.25f + q1.y * 0.75f;
      float gx1 = q1.x * 0.75f + q2.x * 0.25f, gy1 = q1.y * 0.75f + q2.y * 0.25f;
      float gx2 = q1.x * 0.25f + q2.x * 0.75f, gy2 = q1.y * 0.25f + q2.y * 0.75f;
      float gx3 = q2.x * 0.75f + q3.x * 0.25f, gy3 = q2.y * 0.75f + q3.y * 0.25f;
      const size_t ob = obase0 + (size_t)dr2 * 1024;
      *(vfloat4*)(out + ob) = (vfloat4){hx0 * wy0 + gx0 * fh, hx1 * wy0 + gx1 * fh,
                                        hx2 * wy0 + gx2 * fh, hx3 * wy0 + gx3 * fh};
      *(vfloat4*)(out + ob + HWTOT) = (vfloat4){hy0 * wy0 + gy0 * fh, hy1 * wy0 + gy1 * fh,
                                                hy2 * wy0 + gy2 * fh, hy3 * wy0 + gy3 * fh};
    }
    return;
  }

  // generic path (lv >= 2): horizontal indices/weights shared across all rows
  int w0l[4];
  float fw[4];
#pragma unroll
  for (int k = 0; k < 4; ++k) {
    float sw = ((float)(w0pix + k) + 0.5f) * scale - 0.5f;
    float f = floorf(sw);
    fw[k] = sw - f;
    w0l[k] = (int)f + 1;  // shifted LDS col; clamps baked into staging
  }
#pragma unroll
  for (int dr2 = 0; dr2 < 4; ++dr2) {
    const int rr = rr0 + 2 * dr2;
    const int h = (bx << 3) + rr;
    float shf = ((float)h + 0.5f) * scale - 0.5f;
    float f0 = floorf(shf);
    float fh = shf - f0;
    int d0 = (int)f0 - hbase;  // 0..4; vertical clamps baked into staging
    const float2* R0 = rows + d0 * RW;
    const float2* R1 = R0 + RW;
    const float wy0 = 1.0f - fh;
    float o0[4], o1[4];
#pragma unroll
    for (int k = 0; k < 4; ++k) {
      float2 v00 = R0[w0l[k]], v01 = R0[w0l[k] + 1];
      float2 v10 = R1[w0l[k]], v11 = R1[w0l[k] + 1];
      float wx0 = 1.0f - fw[k];
      float tx_ = v00.x * wx0 + v01.x * fw[k];
      float bx_ = v10.x * wx0 + v11.x * fw[k];
      float ty_ = v00.y * wx0 + v01.y * fw[k];
      float by_ = v10.y * wx0 + v11.y * fw[k];
      o0[k] = tx_ * wy0 + bx_ * fh;
      o1[k] = ty_ * wy0 + by_ * fh;
    }
    const size_t ob = obase0 + (size_t)dr2 * 1024;
    *(vfloat4*)(out + ob) = (vfloat4){o0[0], o0[1], o0[2], o0[3]};
    *(vfloat4*)(out + ob + HWTOT) = (vfloat4){o1[0], o1[1], o1[2], o1[3]};
  }
}

extern "C" void kernel_launch(void* const* d_in, const int* in_sizes, int n_in,
                              void* d_out, int out_size, void* d_ws, size_t ws_size,
                              hipStream_t stream) {
  const float* x = (const float*)d_in[0];
  float* out = (float*)d_out;
  float2* pyr = (float2*)d_ws;

  build_levels_1_6<<<dim3(64, 8), 256, 0, stream>>>(x, pyr, out);
  upsample_lv<<<dim3(64, 8, 8), 256, 0, stream>>>(pyr, out);
}